// Round 2
// baseline (89999.756 us; speedup 1.0000x reference)
//
#include <hip/hip_runtime.h>
#include <math.h>

#define NB 8
#define NS 2048
#define NE 768
#define NU 1024
#define NBB 512
#define NH 3072
#define NBS (NB*NS)   // 16384
#define NWG 128

typedef float f32x4v __attribute__((ext_vector_type(4)));
typedef __bf16 bf16x8v __attribute__((ext_vector_type(8)));
typedef unsigned short u16x8v __attribute__((ext_vector_type(8)));
typedef unsigned short u16x4v __attribute__((ext_vector_type(4)));

__device__ __forceinline__ unsigned short f2bf(float f) {
  unsigned int u = __builtin_bit_cast(unsigned int, f);
  u = (u + 0x7fffu + ((u >> 16) & 1u)) >> 16;
  return (unsigned short)u;
}
__device__ __forceinline__ float bf2f(unsigned short h) {
  unsigned int u = ((unsigned int)h) << 16;
  return __builtin_bit_cast(float, u);
}

// ---------------- grid barrier (device-scope, monotonic counter) ----------------
__device__ __forceinline__ void gbar(unsigned* cnt, unsigned target) {
  __syncthreads();
  if (threadIdx.x == 0) {
    __threadfence();                       // release this block's prior writes
    atomicAdd(cnt, 1u);                    // device-scope by default on CDNA
    while (__hip_atomic_load(cnt, __ATOMIC_RELAXED, __HIP_MEMORY_SCOPE_AGENT) < target)
      __builtin_amdgcn_s_sleep(1);
    __threadfence();                       // acquire other blocks' writes
  }
  __syncthreads();
}

// ---------------- transpose kernels (weight prep) ----------------
__global__ __launch_bounds__(256) void tr_f32(const float* __restrict__ in,
                                              float* __restrict__ out, int R, int C) {
  __shared__ float tile[32][33];
  int c0 = blockIdx.x * 32, r0 = blockIdx.y * 32;
  int tx = threadIdx.x, ty = threadIdx.y;  // block (32,8)
  #pragma unroll
  for (int i = 0; i < 32; i += 8)
    tile[ty + i][tx] = in[(long)(r0 + ty + i) * C + c0 + tx];
  __syncthreads();
  #pragma unroll
  for (int i = 0; i < 32; i += 8)
    out[(long)(c0 + ty + i) * R + r0 + tx] = tile[tx][ty + i];
}

__global__ __launch_bounds__(256) void tr_f32_bf16(const float* __restrict__ in,
                                                   unsigned short* __restrict__ out, int R, int C) {
  __shared__ float tile[32][33];
  int c0 = blockIdx.x * 32, r0 = blockIdx.y * 32;
  int tx = threadIdx.x, ty = threadIdx.y;
  #pragma unroll
  for (int i = 0; i < 32; i += 8)
    tile[ty + i][tx] = in[(long)(r0 + ty + i) * C + c0 + tx];
  __syncthreads();
  #pragma unroll
  for (int i = 0; i < 32; i += 8)
    out[(long)(c0 + ty + i) * R + r0 + tx] = f2bf(tile[tx][ty + i]);
}

// transpose + split into bf16 hi/lo pair (for ~fp32-precision GEMM)
__global__ __launch_bounds__(256) void tr_f32_bf16split(const float* __restrict__ in,
    unsigned short* __restrict__ oh, unsigned short* __restrict__ ol, int R, int C) {
  __shared__ float tile[32][33];
  int c0 = blockIdx.x * 32, r0 = blockIdx.y * 32;
  int tx = threadIdx.x, ty = threadIdx.y;
  #pragma unroll
  for (int i = 0; i < 32; i += 8)
    tile[ty + i][tx] = in[(long)(r0 + ty + i) * C + c0 + tx];
  __syncthreads();
  #pragma unroll
  for (int i = 0; i < 32; i += 8) {
    float v = tile[tx][ty + i];
    unsigned short h = f2bf(v);
    long idx = (long)(c0 + ty + i) * R + r0 + tx;
    oh[idx] = h;
    ol[idx] = f2bf(v - bf2f(h));
  }
}

// ---------------- LayerNorm (one wave per row of 768) -> bf16 hi/lo out ----------------
__global__ __launch_bounds__(256) void ln_kernel(const float* __restrict__ in,
    const float* __restrict__ gw, const float* __restrict__ bw,
    unsigned short* __restrict__ outh, unsigned short* __restrict__ outl) {
  int lane = threadIdx.x & 63;
  long row = (long)blockIdx.x * 4 + (threadIdx.x >> 6);
  const float4* rp = (const float4*)(in + row * NE);
  float4 v[3];
  float s = 0.f, sq = 0.f;
  #pragma unroll
  for (int j = 0; j < 3; ++j) {
    v[j] = rp[lane + j * 64];
    s += v[j].x + v[j].y + v[j].z + v[j].w;
    sq += v[j].x*v[j].x + v[j].y*v[j].y + v[j].z*v[j].z + v[j].w*v[j].w;
  }
  #pragma unroll
  for (int m = 1; m < 64; m <<= 1) { s += __shfl_xor(s, m); sq += __shfl_xor(sq, m); }
  float mu = s * (1.f / NE);
  float rs = rsqrtf(sq * (1.f / NE) - mu * mu + 1e-5f);
  #pragma unroll
  for (int j = 0; j < 3; ++j) {
    int c4 = lane + j * 64;
    float4 g4 = ((const float4*)gw)[c4];
    float4 b4 = ((const float4*)bw)[c4];
    float f0 = (v[j].x - mu) * rs * g4.x + b4.x;
    float f1 = (v[j].y - mu) * rs * g4.y + b4.y;
    float f2 = (v[j].z - mu) * rs * g4.z + b4.z;
    float f3 = (v[j].w - mu) * rs * g4.w + b4.w;
    u16x4v oh, ol;
    oh[0] = f2bf(f0); ol[0] = f2bf(f0 - bf2f(oh[0]));
    oh[1] = f2bf(f1); ol[1] = f2bf(f1 - bf2f(oh[1]));
    oh[2] = f2bf(f2); ol[2] = f2bf(f2 - bf2f(oh[2]));
    oh[3] = f2bf(f3); ol[3] = f2bf(f3 - bf2f(oh[3]));
    *(u16x4v*)(outh + row * NE + (long)c4 * 4) = oh;
    *(u16x4v*)(outl + row * NE + (long)c4 * 4) = ol;
  }
}

// ---------------- bf16 MFMA GEMM: C[M,N] = A[M,K] @ Bt[N,K]^T (+bias, epilogue) ---
// EPI 0: Cf = acc + bias            (fp32 out)
// EPI 1: Cb = bf16(gelu(acc+bias))  (bf16 out)
// EPI 2: Cf = acc + bias + res      (fp32 out, residual add; res may alias Cf)
// EPI 3: Cf += acc                  (fp32 accumulate, no bias)
template<int EPI>
__global__ __launch_bounds__(256) void gemm_bf16(
    const unsigned short* __restrict__ A, const unsigned short* __restrict__ Bt,
    const float* __restrict__ bias, const float* res,
    float* Cf, unsigned short* Cb, int M, int N, int K)
{
  __shared__ unsigned short lA[128][72];
  __shared__ unsigned short lB[128][72];
  int tid = threadIdx.x;
  int lane = tid & 63, wave = tid >> 6;
  int wr = wave >> 1, wc = wave & 1;
  int r15 = lane & 15, hi = lane >> 4;
  int ntn = N >> 7;
  long m0 = (long)(blockIdx.x / ntn) << 7;
  long n0 = (long)(blockIdx.x % ntn) << 7;
  f32x4v acc[4][4];
  #pragma unroll
  for (int m = 0; m < 4; ++m)
    #pragma unroll
    for (int n = 0; n < 4; ++n) acc[m][n] = (f32x4v){0.f, 0.f, 0.f, 0.f};

  for (int kt = 0; kt < K; kt += 64) {
    u16x8v ra[4], rb[4];
    #pragma unroll
    for (int i = 0; i < 4; ++i) {
      int c = tid + (i << 8);
      int rw = c >> 3, ko = (c & 7) << 3;
      ra[i] = *(const u16x8v*)(A + (m0 + rw) * K + kt + ko);
      rb[i] = *(const u16x8v*)(Bt + (n0 + rw) * K + kt + ko);
    }
    __syncthreads();
    #pragma unroll
    for (int i = 0; i < 4; ++i) {
      int c = tid + (i << 8);
      int rw = c >> 3, ko = (c & 7) << 3;
      *(u16x8v*)(&lA[rw][ko]) = ra[i];
      *(u16x8v*)(&lB[rw][ko]) = rb[i];
    }
    __syncthreads();
    #pragma unroll
    for (int ks = 0; ks < 64; ks += 32) {
      bf16x8v af[4], bfr[4];
      #pragma unroll
      for (int m = 0; m < 4; ++m)
        af[m] = *(const bf16x8v*)(&lA[wr * 64 + m * 16 + r15][ks + hi * 8]);
      #pragma unroll
      for (int n = 0; n < 4; ++n)
        bfr[n] = *(const bf16x8v*)(&lB[wc * 64 + n * 16 + r15][ks + hi * 8]);
      #pragma unroll
      for (int m = 0; m < 4; ++m)
        #pragma unroll
        for (int n = 0; n < 4; ++n)
          acc[m][n] = __builtin_amdgcn_mfma_f32_16x16x32_bf16(af[m], bfr[n], acc[m][n], 0, 0, 0);
    }
  }
  #pragma unroll
  for (int m = 0; m < 4; ++m) {
    long rbase = m0 + wr * 64 + m * 16 + hi * 4;
    #pragma unroll
    for (int n = 0; n < 4; ++n) {
      long cg = n0 + wc * 64 + n * 16 + r15;
      float bs = (EPI == 3) ? 0.f : bias[cg];
      #pragma unroll
      for (int e = 0; e < 4; ++e) {
        long row = rbase + e;
        float vv = acc[m][n][e] + bs;
        if (EPI == 0) {
          Cf[row * N + cg] = vv;
        } else if (EPI == 1) {
          float gl = 0.5f * vv * (1.f + erff(vv * 0.70710678118f));
          Cb[row * N + cg] = f2bf(gl);
        } else if (EPI == 2) {
          Cf[row * N + cg] = vv + res[row * N + cg];
        } else {
          Cf[row * N + cg] += vv;
        }
      }
    }
  }
}

// ---------------- persistent scan kernel (normal launch, own grid barrier) ------
// grid = 128 WGs x 256 thr; 2 barriers per timestep.
// stage1: WG bx handles j = bx*4+wave (one j per wave), dot over U=1024, 8 batches.
// stage2: WG bx handles v = bx*8..bx*8+7; lane = (head[4], v2[2], jsub[8]).
__global__ __launch_bounds__(256) void scan_kernel(
    const float* __restrict__ pre, const float* __restrict__ WhhT,
    const float* __restrict__ WhT,
    const float* __restrict__ bf1, const float* __restrict__ bf2,
    const float* __restrict__ bta, const float* __restrict__ btb,
    float* hbuf, float* bbf, float* __restrict__ cfc, unsigned* cnt)
{
  int tid = threadIdx.x;
  int lane = tid & 63, wave = tid >> 6;
  int bx = blockIdx.x;
  int j1 = (bx << 2) + wave;
  int head = lane >> 4, v2 = (lane >> 3) & 1, jsub = lane & 7;
  int vg = (bx << 3) + (wave << 1) + v2;
  __shared__ float lpart[4][4][2][8];
  const float4* W14 = (const float4*)(WhhT + (long)j1 * NU);
  const float4* W24 = (const float4*)(WhT + ((long)head * NU + vg) * NBB);
  const float4* h4  = (const float4*)hbuf;
  const float4* bb4 = (const float4*)bbf;
  unsigned bk = 0;

  for (int t = 0; t < NS; ++t) {
    // ---- stage 1: bb = lecun_tanh(pre + h @ W_hh) ----
    float prv[8];
    if (lane == 0) {
      #pragma unroll
      for (int b = 0; b < 8; ++b) prv[b] = pre[((long)b * NS + t) * NBB + j1];
    }
    float a1[8];
    #pragma unroll
    for (int b = 0; b < 8; ++b) a1[b] = 0.f;
    #pragma unroll
    for (int c = 0; c < 4; ++c) {
      int idx = (c << 6) + lane;       // float4 index over U=1024 -> 256
      float4 w = W14[idx];
      #pragma unroll
      for (int b = 0; b < 8; ++b) {
        float4 hv = h4[(b << 8) + idx];
        a1[b] += w.x * hv.x + w.y * hv.y + w.z * hv.z + w.w * hv.w;
      }
    }
    #pragma unroll
    for (int m = 1; m < 64; m <<= 1)
      #pragma unroll
      for (int b = 0; b < 8; ++b) a1[b] += __shfl_xor(a1[b], m);
    if (lane == 0) {
      #pragma unroll
      for (int b = 0; b < 8; ++b) {
        float s = a1[b] + prv[b];
        bbf[b * NBB + j1] = 1.7159f * tanhf(0.666f * s);
      }
    }
    gbar(cnt, (++bk) * NWG);

    // ---- stage 2: heads + h update ----
    float a2[8];
    #pragma unroll
    for (int b = 0; b < 8; ++b) a2[b] = 0.f;
    #pragma unroll
    for (int c = 0; c < 16; ++c) {
      int idx = (jsub << 4) + c;       // float4 index over BB=512 -> 128
      float4 w = W24[idx];
      #pragma unroll
      for (int b = 0; b < 8; ++b) {
        float4 bv = bb4[(b << 7) + idx];
        a2[b] += w.x * bv.x + w.y * bv.y + w.z * bv.z + w.w * bv.w;
      }
    }
    #pragma unroll
    for (int m = 1; m < 8; m <<= 1)
      #pragma unroll
      for (int b = 0; b < 8; ++b) a2[b] += __shfl_xor(a2[b], m);
    if (jsub == 0) {
      #pragma unroll
      for (int b = 0; b < 8; ++b) lpart[wave][head][v2][b] = a2[b];
    }
    __syncthreads();
    if (tid < 64) {
      int vl = tid >> 3, b = tid & 7;
      int wv = vl >> 1, q = vl & 1;
      int vo = (bx << 3) + vl;
      float d1 = lpart[wv][0][q][b] + bf1[vo];
      float d2 = lpart[wv][1][q][b] + bf2[vo];
      float dt = lpart[wv][2][q][b] + bta[vo] + lpart[wv][3][q][b] + btb[vo];
      float f1 = 1.7159f * tanhf(0.666f * d1);
      float f2 = 1.7159f * tanhf(0.666f * d2);
      float ti = 1.f / (1.f + expf(-dt));
      float hn = f1 * (1.f - ti) + ti * f2;
      hbuf[b * NU + vo] = hn;
      if (vo < NE) cfc[((long)b * NS + t) * NE + vo] = hn;
    }
    gbar(cnt, (++bk) * NWG);
  }
}

// ---------------- LIF gate + residual (writes x1 into d_out), copy hx ----------------
__global__ __launch_bounds__(256) void lif_kernel(
    const float* __restrict__ x, const float* __restrict__ cfc,
    const float* __restrict__ thr, const float* __restrict__ leak,
    const float* __restrict__ steep, const float* __restrict__ hbuf,
    float* __restrict__ x1, float* __restrict__ outTail)
{
  long i4 = (long)blockIdx.x * blockDim.x + threadIdx.x;  // float4 index
  float4 xv = ((const float4*)x)[i4];
  float4 cv = ((const float4*)cfc)[i4];
  int col = (int)((i4 << 2) % NE);
  float4 tv = *(const float4*)(thr + col);
  float4 lv = *(const float4*)(leak + col);
  float4 sv = *(const float4*)(steep + col);
  float4 r;
#define LIF1(comp) { \
    float th = fabsf(tv.comp) * 0.1f; \
    float ls = 1.f / (1.f + expf(-lv.comp)); \
    float sp = (sv.comp > 20.f) ? sv.comp : log1pf(expf(sv.comp)); \
    float fire = 1.f / (1.f + expf(-sp * (fabsf(cv.comp) - th))); \
    float gate = fire + ls * (1.f - fire); \
    r.comp = xv.comp + cv.comp * gate; }
  LIF1(x) LIF1(y) LIF1(z) LIF1(w)
#undef LIF1
  ((float4*)x1)[i4] = r;
  if (i4 < (NB * NU / 4)) ((float4*)outTail)[i4] = ((const float4*)hbuf)[i4];
}

// ---------------- launch ----------------
extern "C" void kernel_launch(void* const* d_in, const int* in_sizes, int n_in,
                              void* d_out, int out_size, void* d_ws, size_t ws_size,
                              hipStream_t stream) {
  (void)in_sizes; (void)n_in; (void)out_size; (void)ws_size;
  const float* x     = (const float*)d_in[0];
  const float* hx    = (const float*)d_in[1];
  const float* ln1g  = (const float*)d_in[2];
  const float* ln1b  = (const float*)d_in[3];
  const float* ln2g  = (const float*)d_in[4];
  const float* ln2b  = (const float*)d_in[5];
  const float* Wbb   = (const float*)d_in[6];
  const float* bbb   = (const float*)d_in[7];
  const float* Wff1  = (const float*)d_in[8];
  const float* bff1  = (const float*)d_in[9];
  const float* Wff2  = (const float*)d_in[10];
  const float* bff2  = (const float*)d_in[11];
  const float* Wta   = (const float*)d_in[12];
  const float* btaP  = (const float*)d_in[13];
  const float* Wtb   = (const float*)d_in[14];
  const float* btbP  = (const float*)d_in[15];
  const float* lthr  = (const float*)d_in[16];
  const float* lleak = (const float*)d_in[17];
  const float* lstp  = (const float*)d_in[18];
  const float* W1    = (const float*)d_in[19];
  const float* b1    = (const float*)d_in[20];
  const float* W2    = (const float*)d_in[21];
  const float* b2    = (const float*)d_in[22];

  char* base = (char*)d_ws;
  unsigned short* normedH = (unsigned short*)base;                   // [0, 25165824)
  float* pre   = (float*)(base + 25165824);                          // [25165824, 58720256)
  float* cfc   = (float*)(base + 58720256);                          // [58720256, 109051904)
  unsigned short* gelu = (unsigned short*)base;                      // [0, 100663296) after cfc consumed
  unsigned short* normedL = (unsigned short*)(base + 109051904);     // [109051904, 134217728)
  unsigned short* h2      = (unsigned short*)(base + 109051904);     // same slot, later phase
  unsigned short* wtbbH = (unsigned short*)(base + 134217728);       // 786432
  float* whhT  = (float*)(base + 135004160);                         // 2097152
  float* whT   = (float*)(base + 137101312);                         // 8388608
  unsigned short* w1t = (unsigned short*)(base + 145489920);         // 4718592
  unsigned short* w2t = (unsigned short*)(base + 150208512);         // 4718592
  float* hbuf  = (float*)(base + 154927104);                         // 32768
  float* bbf   = (float*)(base + 154959872);                         // 16384
  unsigned* cnt = (unsigned*)(base + 154976256);                     // 256
  unsigned short* wtbbL = (unsigned short*)(base + 154976512);       // 786432 -> total 155762944
  float* xout  = (float*)d_out;
  float* outTail = xout + (size_t)NBS * NE;
  unsigned short* lnlo_dummy = (unsigned short*)base;                // scratch, overwritten by gelu

  dim3 b328(32, 8);
  // weight prep (transposed, K-contiguous layouts)
  tr_f32_bf16split<<<dim3(512/32, 768/32), b328, 0, stream>>>(Wbb, wtbbH, wtbbL, 768, 512);
  tr_f32<<<dim3(512/32, 1024/32), b328, 0, stream>>>(Wbb + 768*512, whhT, 1024, 512);
  tr_f32<<<dim3(1024/32, 512/32), b328, 0, stream>>>(Wff1, whT + 0*(size_t)NU*NBB, 512, 1024);
  tr_f32<<<dim3(1024/32, 512/32), b328, 0, stream>>>(Wff2, whT + 1*(size_t)NU*NBB, 512, 1024);
  tr_f32<<<dim3(1024/32, 512/32), b328, 0, stream>>>(Wta,  whT + 2*(size_t)NU*NBB, 512, 1024);
  tr_f32<<<dim3(1024/32, 512/32), b328, 0, stream>>>(Wtb,  whT + 3*(size_t)NU*NBB, 512, 1024);
  tr_f32_bf16<<<dim3(3072/32, 768/32), b328, 0, stream>>>(W1, w1t, 768, 3072);
  tr_f32_bf16<<<dim3(768/32, 3072/32), b328, 0, stream>>>(W2, w2t, 3072, 768);

  // LN1 (hi/lo split) + input-projection precompute in ~fp32 precision:
  // pre = nH@wH + nH@wL + nL@wH + b_bb
  ln_kernel<<<NBS/4, 256, 0, stream>>>(x, ln1g, ln1b, normedH, normedL);
  gemm_bf16<0><<<(NBS/128)*(NBB/128), 256, 0, stream>>>(normedH, wtbbH, bbb, nullptr,
                                                        pre, nullptr, NBS, NBB, NE);
  gemm_bf16<3><<<(NBS/128)*(NBB/128), 256, 0, stream>>>(normedH, wtbbL, bbb, nullptr,
                                                        pre, nullptr, NBS, NBB, NE);
  gemm_bf16<3><<<(NBS/128)*(NBB/128), 256, 0, stream>>>(normedL, wtbbH, bbb, nullptr,
                                                        pre, nullptr, NBS, NBB, NE);

  hipMemsetAsync(cnt, 0, 256, stream);
  hipMemcpyAsync(hbuf, hx, (size_t)NB*NU*sizeof(float), hipMemcpyDeviceToDevice, stream);

  scan_kernel<<<NWG, 256, 0, stream>>>(pre, whhT, whT, bff1, bff2, btaP, btbP,
                                       hbuf, bbf, cfc, cnt);

  // LIF gate + residual -> x1 (stored in d_out), plus new_hx copy to output tail
  lif_kernel<<<(NBS*NE/4)/256, 256, 0, stream>>>(x, cfc, lthr, lleak, lstp, hbuf, xout, outTail);
  // LN2 + MLP with fused GELU and residual
  ln_kernel<<<NBS/4, 256, 0, stream>>>(xout, ln2g, ln2b, h2, lnlo_dummy);
  gemm_bf16<1><<<(NBS/128)*(NH/128), 256, 0, stream>>>(h2, w1t, b1, nullptr,
                                                       nullptr, gelu, NBS, NH, NE);
  gemm_bf16<2><<<(NBS/128)*(NE/128), 256, 0, stream>>>(gelu, w2t, b2, xout,
                                                       xout, nullptr, NBS, NE, NH);
}

// Round 3
// 31286.447 us; speedup vs baseline: 2.8766x; 2.8766x over previous
//
#include <hip/hip_runtime.h>
#include <math.h>

#define NB 8
#define NS 2048
#define NE 768
#define NU 1024
#define NBB 512
#define NH 3072
#define NBS (NB*NS)   // 16384
#define NWG 128

typedef float f32x4v __attribute__((ext_vector_type(4)));
typedef __bf16 bf16x8v __attribute__((ext_vector_type(8)));
typedef unsigned short u16x8v __attribute__((ext_vector_type(8)));
typedef unsigned short u16x4v __attribute__((ext_vector_type(4)));

__device__ __forceinline__ unsigned short f2bf(float f) {
  unsigned int u = __builtin_bit_cast(unsigned int, f);
  u = (u + 0x7fffu + ((u >> 16) & 1u)) >> 16;
  return (unsigned short)u;
}
__device__ __forceinline__ float bf2f(unsigned short h) {
  unsigned int u = ((unsigned int)h) << 16;
  return __builtin_bit_cast(float, u);
}

// agent-scope (device) relaxed ops: compile to sc0 sc1 loads/stores (bypass
// L1/L2, coherent at LLC) with NO cache writeback/invalidate instructions.
__device__ __forceinline__ float ald(const float* p) {
  return __hip_atomic_load((const float*)p, __ATOMIC_RELAXED, __HIP_MEMORY_SCOPE_AGENT);
}
__device__ __forceinline__ void ast(float* p, float v) {
  __hip_atomic_store(p, v, __ATOMIC_RELAXED, __HIP_MEMORY_SCOPE_AGENT);
}

// ---------------- hierarchical grid barrier ----------------
// bar[g*32] : 16 group counters (128B apart); bar[512]: root; bar[544]: epoch flag.
// Monotonic counts; __syncthreads drains vmcnt(0) so prior sc-stores are
// LLC-visible before arrival. Spin is read-only on the flag line.
__device__ __forceinline__ void gbar2(unsigned* bar, int gid, unsigned tick) {
  __syncthreads();
  if (threadIdx.x == 0) {
    unsigned old = __hip_atomic_fetch_add(&bar[gid * 32], 1u,
                       __ATOMIC_RELAXED, __HIP_MEMORY_SCOPE_AGENT);
    if (old == 8u * tick - 1u) {               // last arrival of this group
      unsigned o2 = __hip_atomic_fetch_add(&bar[16 * 32], 1u,
                       __ATOMIC_RELAXED, __HIP_MEMORY_SCOPE_AGENT);
      if (o2 == 16u * tick - 1u)               // last group leader
        __hip_atomic_store(&bar[17 * 32], tick,
                       __ATOMIC_RELAXED, __HIP_MEMORY_SCOPE_AGENT);
    }
    while (__hip_atomic_load(&bar[17 * 32],
                       __ATOMIC_RELAXED, __HIP_MEMORY_SCOPE_AGENT) < tick)
      __builtin_amdgcn_s_sleep(2);
  }
  __syncthreads();
}

// ---------------- transpose kernels (weight prep) ----------------
__global__ __launch_bounds__(256) void tr_f32(const float* __restrict__ in,
                                              float* __restrict__ out, int R, int C) {
  __shared__ float tile[32][33];
  int c0 = blockIdx.x * 32, r0 = blockIdx.y * 32;
  int tx = threadIdx.x, ty = threadIdx.y;  // block (32,8)
  #pragma unroll
  for (int i = 0; i < 32; i += 8)
    tile[ty + i][tx] = in[(long)(r0 + ty + i) * C + c0 + tx];
  __syncthreads();
  #pragma unroll
  for (int i = 0; i < 32; i += 8)
    out[(long)(c0 + ty + i) * R + r0 + tx] = tile[tx][ty + i];
}

__global__ __launch_bounds__(256) void tr_f32_bf16(const float* __restrict__ in,
                                                   unsigned short* __restrict__ out, int R, int C) {
  __shared__ float tile[32][33];
  int c0 = blockIdx.x * 32, r0 = blockIdx.y * 32;
  int tx = threadIdx.x, ty = threadIdx.y;
  #pragma unroll
  for (int i = 0; i < 32; i += 8)
    tile[ty + i][tx] = in[(long)(r0 + ty + i) * C + c0 + tx];
  __syncthreads();
  #pragma unroll
  for (int i = 0; i < 32; i += 8)
    out[(long)(c0 + ty + i) * R + r0 + tx] = f2bf(tile[tx][ty + i]);
}

// transpose + split into bf16 hi/lo pair (for ~fp32-precision GEMM)
__global__ __launch_bounds__(256) void tr_f32_bf16split(const float* __restrict__ in,
    unsigned short* __restrict__ oh, unsigned short* __restrict__ ol, int R, int C) {
  __shared__ float tile[32][33];
  int c0 = blockIdx.x * 32, r0 = blockIdx.y * 32;
  int tx = threadIdx.x, ty = threadIdx.y;
  #pragma unroll
  for (int i = 0; i < 32; i += 8)
    tile[ty + i][tx] = in[(long)(r0 + ty + i) * C + c0 + tx];
  __syncthreads();
  #pragma unroll
  for (int i = 0; i < 32; i += 8) {
    float v = tile[tx][ty + i];
    unsigned short h = f2bf(v);
    long idx = (long)(c0 + ty + i) * R + r0 + tx;
    oh[idx] = h;
    ol[idx] = f2bf(v - bf2f(h));
  }
}

// ---------------- LayerNorm (one wave per row of 768) -> bf16 hi/lo out ----------------
__global__ __launch_bounds__(256) void ln_kernel(const float* __restrict__ in,
    const float* __restrict__ gw, const float* __restrict__ bw,
    unsigned short* __restrict__ outh, unsigned short* __restrict__ outl) {
  int lane = threadIdx.x & 63;
  long row = (long)blockIdx.x * 4 + (threadIdx.x >> 6);
  const float4* rp = (const float4*)(in + row * NE);
  float4 v[3];
  float s = 0.f, sq = 0.f;
  #pragma unroll
  for (int j = 0; j < 3; ++j) {
    v[j] = rp[lane + j * 64];
    s += v[j].x + v[j].y + v[j].z + v[j].w;
    sq += v[j].x*v[j].x + v[j].y*v[j].y + v[j].z*v[j].z + v[j].w*v[j].w;
  }
  #pragma unroll
  for (int m = 1; m < 64; m <<= 1) { s += __shfl_xor(s, m); sq += __shfl_xor(sq, m); }
  float mu = s * (1.f / NE);
  float rs = rsqrtf(sq * (1.f / NE) - mu * mu + 1e-5f);
  #pragma unroll
  for (int j = 0; j < 3; ++j) {
    int c4 = lane + j * 64;
    float4 g4 = ((const float4*)gw)[c4];
    float4 b4 = ((const float4*)bw)[c4];
    float f0 = (v[j].x - mu) * rs * g4.x + b4.x;
    float f1 = (v[j].y - mu) * rs * g4.y + b4.y;
    float f2 = (v[j].z - mu) * rs * g4.z + b4.z;
    float f3 = (v[j].w - mu) * rs * g4.w + b4.w;
    u16x4v oh, ol;
    oh[0] = f2bf(f0); ol[0] = f2bf(f0 - bf2f(oh[0]));
    oh[1] = f2bf(f1); ol[1] = f2bf(f1 - bf2f(oh[1]));
    oh[2] = f2bf(f2); ol[2] = f2bf(f2 - bf2f(oh[2]));
    oh[3] = f2bf(f3); ol[3] = f2bf(f3 - bf2f(oh[3]));
    *(u16x4v*)(outh + row * NE + (long)c4 * 4) = oh;
    *(u16x4v*)(outl + row * NE + (long)c4 * 4) = ol;
  }
}

// ---------------- bf16 MFMA GEMM: C[M,N] = A[M,K] @ Bt[N,K]^T (+bias, epilogue) ---
// EPI 0: Cf = acc + bias            (fp32 out)
// EPI 1: Cb = bf16(gelu(acc+bias))  (bf16 out)
// EPI 2: Cf = acc + bias + res      (fp32 out, residual add; res may alias Cf)
// EPI 3: Cf += acc                  (fp32 accumulate, no bias)
template<int EPI>
__global__ __launch_bounds__(256) void gemm_bf16(
    const unsigned short* __restrict__ A, const unsigned short* __restrict__ Bt,
    const float* __restrict__ bias, const float* res,
    float* Cf, unsigned short* Cb, int M, int N, int K)
{
  __shared__ unsigned short lA[128][72];
  __shared__ unsigned short lB[128][72];
  int tid = threadIdx.x;
  int lane = tid & 63, wave = tid >> 6;
  int wr = wave >> 1, wc = wave & 1;
  int r15 = lane & 15, hi = lane >> 4;
  int ntn = N >> 7;
  long m0 = (long)(blockIdx.x / ntn) << 7;
  long n0 = (long)(blockIdx.x % ntn) << 7;
  f32x4v acc[4][4];
  #pragma unroll
  for (int m = 0; m < 4; ++m)
    #pragma unroll
    for (int n = 0; n < 4; ++n) acc[m][n] = (f32x4v){0.f, 0.f, 0.f, 0.f};

  for (int kt = 0; kt < K; kt += 64) {
    u16x8v ra[4], rb[4];
    #pragma unroll
    for (int i = 0; i < 4; ++i) {
      int c = tid + (i << 8);
      int rw = c >> 3, ko = (c & 7) << 3;
      ra[i] = *(const u16x8v*)(A + (m0 + rw) * K + kt + ko);
      rb[i] = *(const u16x8v*)(Bt + (n0 + rw) * K + kt + ko);
    }
    __syncthreads();
    #pragma unroll
    for (int i = 0; i < 4; ++i) {
      int c = tid + (i << 8);
      int rw = c >> 3, ko = (c & 7) << 3;
      *(u16x8v*)(&lA[rw][ko]) = ra[i];
      *(u16x8v*)(&lB[rw][ko]) = rb[i];
    }
    __syncthreads();
    #pragma unroll
    for (int ks = 0; ks < 64; ks += 32) {
      bf16x8v af[4], bfr[4];
      #pragma unroll
      for (int m = 0; m < 4; ++m)
        af[m] = *(const bf16x8v*)(&lA[wr * 64 + m * 16 + r15][ks + hi * 8]);
      #pragma unroll
      for (int n = 0; n < 4; ++n)
        bfr[n] = *(const bf16x8v*)(&lB[wc * 64 + n * 16 + r15][ks + hi * 8]);
      #pragma unroll
      for (int m = 0; m < 4; ++m)
        #pragma unroll
        for (int n = 0; n < 4; ++n)
          acc[m][n] = __builtin_amdgcn_mfma_f32_16x16x32_bf16(af[m], bfr[n], acc[m][n], 0, 0, 0);
    }
  }
  #pragma unroll
  for (int m = 0; m < 4; ++m) {
    long rbase = m0 + wr * 64 + m * 16 + hi * 4;
    #pragma unroll
    for (int n = 0; n < 4; ++n) {
      long cg = n0 + wc * 64 + n * 16 + r15;
      float bs = (EPI == 3) ? 0.f : bias[cg];
      #pragma unroll
      for (int e = 0; e < 4; ++e) {
        long row = rbase + e;
        float vv = acc[m][n][e] + bs;
        if (EPI == 0) {
          Cf[row * N + cg] = vv;
        } else if (EPI == 1) {
          float gl = 0.5f * vv * (1.f + erff(vv * 0.70710678118f));
          Cb[row * N + cg] = f2bf(gl);
        } else if (EPI == 2) {
          Cf[row * N + cg] = vv + res[row * N + cg];
        } else {
          Cf[row * N + cg] += vv;
        }
      }
    }
  }
}

// ---------------- persistent scan kernel ----------------
// 128 WGs x 256 thr; 2 hierarchical barriers per timestep.
// Exchange data (hbuf/bbf) via agent-scope sc0sc1 ops, staged into LDS once
// per block per stage. Weights use normal cached loads (stay L2-resident:
// no fences, no invalidates anywhere).
__global__ __launch_bounds__(256) void scan_kernel(
    const float* __restrict__ pre, const float* __restrict__ WhhT,
    const float* __restrict__ WhT,
    const float* __restrict__ bf1, const float* __restrict__ bf2,
    const float* __restrict__ bta, const float* __restrict__ btb,
    const float* __restrict__ hx,
    float* hbuf, float* bbf, float* __restrict__ cfc, unsigned* bar)
{
  __shared__ float lsd[NB * NU];            // h staging (32KB); bb reuses first 16KB
  __shared__ float lpart[4][4][2][8];
  int tid = threadIdx.x;
  int lane = tid & 63, wave = tid >> 6;
  int bx = blockIdx.x;
  int gid = bx >> 3;
  int j1 = (bx << 2) + wave;
  int head = lane >> 4, v2 = (lane >> 3) & 1, jsub = lane & 7;
  int vg = (bx << 3) + (wave << 1) + v2;
  const float4* W14 = (const float4*)(WhhT + (long)j1 * NU);
  const float4* W24 = (const float4*)(WhT + ((long)head * NU + vg) * NBB);
  const float4* ls4 = (const float4*)lsd;
  unsigned tick = 0;

  // hoist this wave's Whh row (4KB across 64 lanes -> 4 float4/lane)
  float4 wreg[4];
  #pragma unroll
  for (int c = 0; c < 4; ++c) wreg[c] = W14[(c << 6) + lane];

  // tail-update constants
  int vl = tid >> 3, bq = tid & 7;
  int wv = vl >> 1, qq = vl & 1;
  int vo = (bx << 3) + vl;
  float cb1 = 0.f, cb2 = 0.f, cbt = 0.f;
  if (tid < 64) { cb1 = bf1[vo]; cb2 = bf2[vo]; cbt = bta[vo] + btb[vo]; }

  // init h state (sc-stores so later sc-loads observe it)
  if (tid < 64) ast(&hbuf[(bx << 6) + tid], hx[(bx << 6) + tid]);

  float prv[8];
  if (lane == 0) {
    #pragma unroll
    for (int b = 0; b < 8; ++b) prv[b] = pre[((long)b * NS) * NBB + j1];
  }
  gbar2(bar, gid, ++tick);

  for (int t = 0; t < NS; ++t) {
    // ---- stage h into LDS (batched sc-loads: one latency exposure) ----
    {
      float rv[32];
      #pragma unroll
      for (int i = 0; i < 32; ++i) rv[i] = ald(&hbuf[(i << 8) + tid]);
      #pragma unroll
      for (int i = 0; i < 32; ++i) lsd[(i << 8) + tid] = rv[i];
    }
    __syncthreads();

    // ---- stage 1: bb = lecun_tanh(pre + h @ W_hh) ----
    float a1[8];
    #pragma unroll
    for (int b = 0; b < 8; ++b) a1[b] = 0.f;
    #pragma unroll
    for (int c = 0; c < 4; ++c) {
      int idx = (c << 6) + lane;
      float4 w = wreg[c];
      #pragma unroll
      for (int b = 0; b < 8; ++b) {
        float4 hv = ls4[(b << 8) + idx];
        a1[b] += w.x * hv.x + w.y * hv.y + w.z * hv.z + w.w * hv.w;
      }
    }
    #pragma unroll
    for (int m = 1; m < 64; m <<= 1)
      #pragma unroll
      for (int b = 0; b < 8; ++b) a1[b] += __shfl_xor(a1[b], m);
    if (lane == 0) {
      #pragma unroll
      for (int b = 0; b < 8; ++b) {
        float s = a1[b] + prv[b];
        ast(&bbf[b * NBB + j1], 1.7159f * tanhf(0.666f * s));
      }
    }
    gbar2(bar, gid, ++tick);

    // ---- stage bb into LDS ----
    {
      float rv[16];
      #pragma unroll
      for (int i = 0; i < 16; ++i) rv[i] = ald(&bbf[(i << 8) + tid]);
      #pragma unroll
      for (int i = 0; i < 16; ++i) lsd[(i << 8) + tid] = rv[i];
    }
    __syncthreads();

    // ---- stage 2: heads + h update ----
    float a2[8];
    #pragma unroll
    for (int b = 0; b < 8; ++b) a2[b] = 0.f;
    #pragma unroll
    for (int c = 0; c < 16; ++c) {
      int idx = (jsub << 4) + c;
      float4 w = W24[idx];
      #pragma unroll
      for (int b = 0; b < 8; ++b) {
        float4 bv = ls4[(b << 7) + idx];
        a2[b] += w.x * bv.x + w.y * bv.y + w.z * bv.z + w.w * bv.w;
      }
    }
    #pragma unroll
    for (int m = 1; m < 8; m <<= 1)
      #pragma unroll
      for (int b = 0; b < 8; ++b) a2[b] += __shfl_xor(a2[b], m);
    if (jsub == 0) {
      #pragma unroll
      for (int b = 0; b < 8; ++b) lpart[wave][head][v2][b] = a2[b];
    }
    __syncthreads();
    if (tid < 64) {
      float d1 = lpart[wv][0][qq][bq] + cb1;
      float d2 = lpart[wv][1][qq][bq] + cb2;
      float dt = lpart[wv][2][qq][bq] + lpart[wv][3][qq][bq] + cbt;
      float f1 = 1.7159f * tanhf(0.666f * d1);
      float f2 = 1.7159f * tanhf(0.666f * d2);
      float ti = 1.f / (1.f + expf(-dt));
      float hn = f1 * (1.f - ti) + ti * f2;
      ast(&hbuf[bq * NU + vo], hn);
      if (vo < NE) cfc[((long)bq * NS + t) * NE + vo] = hn;   // normal store (read post-kernel)
    }
    // prefetch next step's pre while waiting is cheap (normal cached load)
    if (lane == 0 && t + 1 < NS) {
      #pragma unroll
      for (int b = 0; b < 8; ++b) prv[b] = pre[((long)b * NS + t + 1) * NBB + j1];
    }
    gbar2(bar, gid, ++tick);
  }
}

// ---------------- LIF gate + residual (writes x1 into d_out), copy hx ----------------
__global__ __launch_bounds__(256) void lif_kernel(
    const float* __restrict__ x, const float* __restrict__ cfc,
    const float* __restrict__ thr, const float* __restrict__ leak,
    const float* __restrict__ steep, const float* __restrict__ hbuf,
    float* __restrict__ x1, float* __restrict__ outTail)
{
  long i4 = (long)blockIdx.x * blockDim.x + threadIdx.x;  // float4 index
  float4 xv = ((const float4*)x)[i4];
  float4 cv = ((const float4*)cfc)[i4];
  int col = (int)((i4 << 2) % NE);
  float4 tv = *(const float4*)(thr + col);
  float4 lv = *(const float4*)(leak + col);
  float4 sv = *(const float4*)(steep + col);
  float4 r;
#define LIF1(comp) { \
    float th = fabsf(tv.comp) * 0.1f; \
    float ls = 1.f / (1.f + expf(-lv.comp)); \
    float sp = (sv.comp > 20.f) ? sv.comp : log1pf(expf(sv.comp)); \
    float fire = 1.f / (1.f + expf(-sp * (fabsf(cv.comp) - th))); \
    float gate = fire + ls * (1.f - fire); \
    r.comp = xv.comp + cv.comp * gate; }
  LIF1(x) LIF1(y) LIF1(z) LIF1(w)
#undef LIF1
  ((float4*)x1)[i4] = r;
  if (i4 < (NB * NU / 4)) {
    // hbuf was written with sc stores; read it back with sc loads
    const float* hp = hbuf + (i4 << 2);
    float4 hv; hv.x = ald(hp); hv.y = ald(hp + 1); hv.z = ald(hp + 2); hv.w = ald(hp + 3);
    ((float4*)outTail)[i4] = hv;
  }
}

// ---------------- launch ----------------
extern "C" void kernel_launch(void* const* d_in, const int* in_sizes, int n_in,
                              void* d_out, int out_size, void* d_ws, size_t ws_size,
                              hipStream_t stream) {
  (void)in_sizes; (void)n_in; (void)out_size; (void)ws_size;
  const float* x     = (const float*)d_in[0];
  const float* hx    = (const float*)d_in[1];
  const float* ln1g  = (const float*)d_in[2];
  const float* ln1b  = (const float*)d_in[3];
  const float* ln2g  = (const float*)d_in[4];
  const float* ln2b  = (const float*)d_in[5];
  const float* Wbb   = (const float*)d_in[6];
  const float* bbb   = (const float*)d_in[7];
  const float* Wff1  = (const float*)d_in[8];
  const float* bff1  = (const float*)d_in[9];
  const float* Wff2  = (const float*)d_in[10];
  const float* bff2  = (const float*)d_in[11];
  const float* Wta   = (const float*)d_in[12];
  const float* btaP  = (const float*)d_in[13];
  const float* Wtb   = (const float*)d_in[14];
  const float* btbP  = (const float*)d_in[15];
  const float* lthr  = (const float*)d_in[16];
  const float* lleak = (const float*)d_in[17];
  const float* lstp  = (const float*)d_in[18];
  const float* W1    = (const float*)d_in[19];
  const float* b1    = (const float*)d_in[20];
  const float* W2    = (const float*)d_in[21];
  const float* b2    = (const float*)d_in[22];

  char* base = (char*)d_ws;
  unsigned short* normedH = (unsigned short*)base;                   // [0, 25165824)
  float* pre   = (float*)(base + 25165824);                          // [25165824, 58720256)
  float* cfc   = (float*)(base + 58720256);                          // [58720256, 109051904)
  unsigned short* gelu = (unsigned short*)base;                      // [0, 100663296) after cfc consumed
  unsigned short* normedL = (unsigned short*)(base + 109051904);     // [109051904, 134217728)
  unsigned short* h2      = (unsigned short*)(base + 109051904);     // same slot, later phase
  unsigned short* wtbbH = (unsigned short*)(base + 134217728);       // 786432
  float* whhT  = (float*)(base + 135004160);                         // 2097152
  float* whT   = (float*)(base + 137101312);                         // 8388608
  unsigned short* w1t = (unsigned short*)(base + 145489920);         // 4718592
  unsigned short* w2t = (unsigned short*)(base + 150208512);         // 4718592
  float* hbuf  = (float*)(base + 154927104);                         // 32768
  float* bbf   = (float*)(base + 154959872);                         // 16384
  unsigned* bar = (unsigned*)(base + 154976256);                     // 4096 (barrier region)
  unsigned short* wtbbL = (unsigned short*)(base + 154980352);       // 786432 -> end 155766784
  float* xout  = (float*)d_out;
  float* outTail = xout + (size_t)NBS * NE;
  unsigned short* lnlo_dummy = (unsigned short*)base;                // scratch, overwritten by gelu

  dim3 b328(32, 8);
  // weight prep (transposed, K-contiguous layouts)
  tr_f32_bf16split<<<dim3(512/32, 768/32), b328, 0, stream>>>(Wbb, wtbbH, wtbbL, 768, 512);
  tr_f32<<<dim3(512/32, 1024/32), b328, 0, stream>>>(Wbb + 768*512, whhT, 1024, 512);
  tr_f32<<<dim3(1024/32, 512/32), b328, 0, stream>>>(Wff1, whT + 0*(size_t)NU*NBB, 512, 1024);
  tr_f32<<<dim3(1024/32, 512/32), b328, 0, stream>>>(Wff2, whT + 1*(size_t)NU*NBB, 512, 1024);
  tr_f32<<<dim3(1024/32, 512/32), b328, 0, stream>>>(Wta,  whT + 2*(size_t)NU*NBB, 512, 1024);
  tr_f32<<<dim3(1024/32, 512/32), b328, 0, stream>>>(Wtb,  whT + 3*(size_t)NU*NBB, 512, 1024);
  tr_f32_bf16<<<dim3(3072/32, 768/32), b328, 0, stream>>>(W1, w1t, 768, 3072);
  tr_f32_bf16<<<dim3(768/32, 3072/32), b328, 0, stream>>>(W2, w2t, 3072, 768);

  // LN1 (hi/lo split) + input-projection precompute in ~fp32 precision:
  // pre = nH@wH + nH@wL + nL@wH + b_bb
  ln_kernel<<<NBS/4, 256, 0, stream>>>(x, ln1g, ln1b, normedH, normedL);
  gemm_bf16<0><<<(NBS/128)*(NBB/128), 256, 0, stream>>>(normedH, wtbbH, bbb, nullptr,
                                                        pre, nullptr, NBS, NBB, NE);
  gemm_bf16<3><<<(NBS/128)*(NBB/128), 256, 0, stream>>>(normedH, wtbbL, bbb, nullptr,
                                                        pre, nullptr, NBS, NBB, NE);
  gemm_bf16<3><<<(NBS/128)*(NBB/128), 256, 0, stream>>>(normedL, wtbbH, bbb, nullptr,
                                                        pre, nullptr, NBS, NBB, NE);

  hipMemsetAsync(bar, 0, 4096, stream);

  scan_kernel<<<NWG, 256, 0, stream>>>(pre, whhT, whT, bff1, bff2, btaP, btbP, hx,
                                       hbuf, bbf, cfc, bar);

  // LIF gate + residual -> x1 (stored in d_out), plus new_hx copy to output tail
  lif_kernel<<<(NBS*NE/4)/256, 256, 0, stream>>>(x, cfc, lthr, lleak, lstp, hbuf, xout, outTail);
  // LN2 + MLP with fused GELU and residual
  ln_kernel<<<NBS/4, 256, 0, stream>>>(xout, ln2g, ln2b, h2, lnlo_dummy);
  gemm_bf16<1><<<(NBS/128)*(NH/128), 256, 0, stream>>>(h2, w1t, b1, nullptr,
                                                       nullptr, gelu, NBS, NH, NE);
  gemm_bf16<2><<<(NBS/128)*(NE/128), 256, 0, stream>>>(gelu, w2t, b2, xout,
                                                       xout, nullptr, NBS, NE, NH);
}

// Round 4
// 23803.558 us; speedup vs baseline: 3.7809x; 1.3144x over previous
//
#include <hip/hip_runtime.h>
#include <math.h>

#define NB 8
#define NS 2048
#define NE 768
#define NU 1024
#define NBB 512
#define NH 3072
#define NBS (NB*NS)   // 16384
#define NWG 128

typedef float f32x4v __attribute__((ext_vector_type(4)));
typedef __bf16 bf16x8v __attribute__((ext_vector_type(8)));
typedef unsigned short u16x8v __attribute__((ext_vector_type(8)));
typedef unsigned short u16x4v __attribute__((ext_vector_type(4)));

__device__ __forceinline__ unsigned short f2bf(float f) {
  unsigned int u = __builtin_bit_cast(unsigned int, f);
  u = (u + 0x7fffu + ((u >> 16) & 1u)) >> 16;
  return (unsigned short)u;
}
__device__ __forceinline__ float bf2f(unsigned short h) {
  unsigned int u = ((unsigned int)h) << 16;
  return __builtin_bit_cast(float, u);
}

// agent-scope (device) relaxed ops: compile to sc0 sc1 loads/stores (coherent
// at LLC, no L2 writeback/invalidate instructions).
__device__ __forceinline__ float ald(const float* p) {
  return __hip_atomic_load((const float*)p, __ATOMIC_RELAXED, __HIP_MEMORY_SCOPE_AGENT);
}
__device__ __forceinline__ void ast(float* p, float v) {
  __hip_atomic_store(p, v, __ATOMIC_RELAXED, __HIP_MEMORY_SCOPE_AGENT);
}
__device__ __forceinline__ float2 ald2(const float* p) {
  unsigned long long v = __hip_atomic_load((const unsigned long long*)p,
                             __ATOMIC_RELAXED, __HIP_MEMORY_SCOPE_AGENT);
  return __builtin_bit_cast(float2, v);
}

// ---------------- flat slot grid barrier ----------------
// slot[bx*4]: per-block monotonic tick (16B spacing). Arrival = one relaxed
// agent store (prior sc-stores drained by __syncthreads' vmcnt(0)). Wave 0
// polls all 128 slots (2 per lane) + wave-min reduce. No RMW, no chains.
__device__ __forceinline__ void gbar3(unsigned* slots, int bx, unsigned tick) {
  __syncthreads();
  int tid = threadIdx.x;
  if (tid == 0)
    __hip_atomic_store(&slots[bx * 4], tick, __ATOMIC_RELAXED, __HIP_MEMORY_SCOPE_AGENT);
  if (tid < 64) {
    unsigned m;
    do {
      unsigned a = __hip_atomic_load(&slots[tid * 4], __ATOMIC_RELAXED, __HIP_MEMORY_SCOPE_AGENT);
      unsigned b = __hip_atomic_load(&slots[(tid + 64) * 4], __ATOMIC_RELAXED, __HIP_MEMORY_SCOPE_AGENT);
      m = a < b ? a : b;
      #pragma unroll
      for (int s = 1; s < 64; s <<= 1) {
        unsigned o = __shfl_xor(m, s);
        m = m < o ? m : o;
      }
      if (m < tick) __builtin_amdgcn_s_sleep(1);
    } while (m < tick);
  }
  __syncthreads();
}

// ---------------- transpose kernels (weight prep) ----------------
__global__ __launch_bounds__(256) void tr_f32(const float* __restrict__ in,
                                              float* __restrict__ out, int R, int C) {
  __shared__ float tile[32][33];
  int c0 = blockIdx.x * 32, r0 = blockIdx.y * 32;
  int tx = threadIdx.x, ty = threadIdx.y;  // block (32,8)
  #pragma unroll
  for (int i = 0; i < 32; i += 8)
    tile[ty + i][tx] = in[(long)(r0 + ty + i) * C + c0 + tx];
  __syncthreads();
  #pragma unroll
  for (int i = 0; i < 32; i += 8)
    out[(long)(c0 + ty + i) * R + r0 + tx] = tile[tx][ty + i];
}

__global__ __launch_bounds__(256) void tr_f32_bf16(const float* __restrict__ in,
                                                   unsigned short* __restrict__ out, int R, int C) {
  __shared__ float tile[32][33];
  int c0 = blockIdx.x * 32, r0 = blockIdx.y * 32;
  int tx = threadIdx.x, ty = threadIdx.y;
  #pragma unroll
  for (int i = 0; i < 32; i += 8)
    tile[ty + i][tx] = in[(long)(r0 + ty + i) * C + c0 + tx];
  __syncthreads();
  #pragma unroll
  for (int i = 0; i < 32; i += 8)
    out[(long)(c0 + ty + i) * R + r0 + tx] = f2bf(tile[tx][ty + i]);
}

// transpose + split into bf16 hi/lo pair (for ~fp32-precision GEMM)
__global__ __launch_bounds__(256) void tr_f32_bf16split(const float* __restrict__ in,
    unsigned short* __restrict__ oh, unsigned short* __restrict__ ol, int R, int C) {
  __shared__ float tile[32][33];
  int c0 = blockIdx.x * 32, r0 = blockIdx.y * 32;
  int tx = threadIdx.x, ty = threadIdx.y;
  #pragma unroll
  for (int i = 0; i < 32; i += 8)
    tile[ty + i][tx] = in[(long)(r0 + ty + i) * C + c0 + tx];
  __syncthreads();
  #pragma unroll
  for (int i = 0; i < 32; i += 8) {
    float v = tile[tx][ty + i];
    unsigned short h = f2bf(v);
    long idx = (long)(c0 + ty + i) * R + r0 + tx;
    oh[idx] = h;
    ol[idx] = f2bf(v - bf2f(h));
  }
}

// ---------------- LayerNorm (one wave per row of 768) -> bf16 hi/lo out ----------------
__global__ __launch_bounds__(256) void ln_kernel(const float* __restrict__ in,
    const float* __restrict__ gw, const float* __restrict__ bw,
    unsigned short* __restrict__ outh, unsigned short* __restrict__ outl) {
  int lane = threadIdx.x & 63;
  long row = (long)blockIdx.x * 4 + (threadIdx.x >> 6);
  const float4* rp = (const float4*)(in + row * NE);
  float4 v[3];
  float s = 0.f, sq = 0.f;
  #pragma unroll
  for (int j = 0; j < 3; ++j) {
    v[j] = rp[lane + j * 64];
    s += v[j].x + v[j].y + v[j].z + v[j].w;
    sq += v[j].x*v[j].x + v[j].y*v[j].y + v[j].z*v[j].z + v[j].w*v[j].w;
  }
  #pragma unroll
  for (int m = 1; m < 64; m <<= 1) { s += __shfl_xor(s, m); sq += __shfl_xor(sq, m); }
  float mu = s * (1.f / NE);
  float rs = rsqrtf(sq * (1.f / NE) - mu * mu + 1e-5f);
  #pragma unroll
  for (int j = 0; j < 3; ++j) {
    int c4 = lane + j * 64;
    float4 g4 = ((const float4*)gw)[c4];
    float4 b4 = ((const float4*)bw)[c4];
    float f0 = (v[j].x - mu) * rs * g4.x + b4.x;
    float f1 = (v[j].y - mu) * rs * g4.y + b4.y;
    float f2 = (v[j].z - mu) * rs * g4.z + b4.z;
    float f3 = (v[j].w - mu) * rs * g4.w + b4.w;
    u16x4v oh, ol;
    oh[0] = f2bf(f0); ol[0] = f2bf(f0 - bf2f(oh[0]));
    oh[1] = f2bf(f1); ol[1] = f2bf(f1 - bf2f(oh[1]));
    oh[2] = f2bf(f2); ol[2] = f2bf(f2 - bf2f(oh[2]));
    oh[3] = f2bf(f3); ol[3] = f2bf(f3 - bf2f(oh[3]));
    *(u16x4v*)(outh + row * NE + (long)c4 * 4) = oh;
    *(u16x4v*)(outl + row * NE + (long)c4 * 4) = ol;
  }
}

// ---------------- bf16 MFMA GEMM: C[M,N] = A[M,K] @ Bt[N,K]^T (+bias, epilogue) ---
// EPI 0: Cf = acc + bias            (fp32 out)
// EPI 1: Cb = bf16(gelu(acc+bias))  (bf16 out)
// EPI 2: Cf = acc + bias + res      (fp32 out, residual add; res may alias Cf)
// EPI 3: Cf += acc                  (fp32 accumulate, no bias)
template<int EPI>
__global__ __launch_bounds__(256) void gemm_bf16(
    const unsigned short* __restrict__ A, const unsigned short* __restrict__ Bt,
    const float* __restrict__ bias, const float* res,
    float* Cf, unsigned short* Cb, int M, int N, int K)
{
  __shared__ unsigned short lA[128][72];
  __shared__ unsigned short lB[128][72];
  int tid = threadIdx.x;
  int lane = tid & 63, wave = tid >> 6;
  int wr = wave >> 1, wc = wave & 1;
  int r15 = lane & 15, hi = lane >> 4;
  int ntn = N >> 7;
  long m0 = (long)(blockIdx.x / ntn) << 7;
  long n0 = (long)(blockIdx.x % ntn) << 7;
  f32x4v acc[4][4];
  #pragma unroll
  for (int m = 0; m < 4; ++m)
    #pragma unroll
    for (int n = 0; n < 4; ++n) acc[m][n] = (f32x4v){0.f, 0.f, 0.f, 0.f};

  for (int kt = 0; kt < K; kt += 64) {
    u16x8v ra[4], rb[4];
    #pragma unroll
    for (int i = 0; i < 4; ++i) {
      int c = tid + (i << 8);
      int rw = c >> 3, ko = (c & 7) << 3;
      ra[i] = *(const u16x8v*)(A + (m0 + rw) * K + kt + ko);
      rb[i] = *(const u16x8v*)(Bt + (n0 + rw) * K + kt + ko);
    }
    __syncthreads();
    #pragma unroll
    for (int i = 0; i < 4; ++i) {
      int c = tid + (i << 8);
      int rw = c >> 3, ko = (c & 7) << 3;
      *(u16x8v*)(&lA[rw][ko]) = ra[i];
      *(u16x8v*)(&lB[rw][ko]) = rb[i];
    }
    __syncthreads();
    #pragma unroll
    for (int ks = 0; ks < 64; ks += 32) {
      bf16x8v af[4], bfr[4];
      #pragma unroll
      for (int m = 0; m < 4; ++m)
        af[m] = *(const bf16x8v*)(&lA[wr * 64 + m * 16 + r15][ks + hi * 8]);
      #pragma unroll
      for (int n = 0; n < 4; ++n)
        bfr[n] = *(const bf16x8v*)(&lB[wc * 64 + n * 16 + r15][ks + hi * 8]);
      #pragma unroll
      for (int m = 0; m < 4; ++m)
        #pragma unroll
        for (int n = 0; n < 4; ++n)
          acc[m][n] = __builtin_amdgcn_mfma_f32_16x16x32_bf16(af[m], bfr[n], acc[m][n], 0, 0, 0);
    }
  }
  #pragma unroll
  for (int m = 0; m < 4; ++m) {
    long rbase = m0 + wr * 64 + m * 16 + hi * 4;
    #pragma unroll
    for (int n = 0; n < 4; ++n) {
      long cg = n0 + wc * 64 + n * 16 + r15;
      float bs = (EPI == 3) ? 0.f : bias[cg];
      #pragma unroll
      for (int e = 0; e < 4; ++e) {
        long row = rbase + e;
        float vv = acc[m][n][e] + bs;
        if (EPI == 0) {
          Cf[row * N + cg] = vv;
        } else if (EPI == 1) {
          float gl = 0.5f * vv * (1.f + erff(vv * 0.70710678118f));
          Cb[row * N + cg] = f2bf(gl);
        } else if (EPI == 2) {
          Cf[row * N + cg] = vv + res[row * N + cg];
        } else {
          Cf[row * N + cg] += vv;
        }
      }
    }
  }
}

// ---------------- persistent scan kernel ----------------
// 128 WGs x 256 thr; 2 slot barriers per timestep.
// Exchange data (hbuf/bbf) via agent-scope sc ops, staged into LDS per stage.
// Weights use normal cached loads (L2-resident; no fences anywhere).
__global__ __launch_bounds__(256) void scan_kernel(
    const float* __restrict__ pre, const float* __restrict__ WhhT,
    const float* __restrict__ WhT,
    const float* __restrict__ bf1, const float* __restrict__ bf2,
    const float* __restrict__ bta, const float* __restrict__ btb,
    const float* __restrict__ hx,
    float* hbuf, float* bbf, float* __restrict__ cfc, unsigned* bar)
{
  __shared__ float lsd[NB * NU];            // h staging (32KB); bb reuses first 16KB
  __shared__ float lpart[4][4][2][8];
  int tid = threadIdx.x;
  int lane = tid & 63, wave = tid >> 6;
  int bx = blockIdx.x;
  int j1 = (bx << 2) + wave;
  int head = lane >> 4, v2 = (lane >> 3) & 1, jsub = lane & 7;
  int vg = (bx << 3) + (wave << 1) + v2;
  const float4* W14 = (const float4*)(WhhT + (long)j1 * NU);
  const float4* W24 = (const float4*)(WhT + ((long)head * NU + vg) * NBB);
  const float4* ls4 = (const float4*)lsd;
  float2* ls2 = (float2*)lsd;
  unsigned tick = 0;

  // hoist this wave's Whh row (4KB across 64 lanes -> 4 float4/lane)
  float4 wreg[4];
  #pragma unroll
  for (int c = 0; c < 4; ++c) wreg[c] = W14[(c << 6) + lane];

  // tail-update constants
  int vl = tid >> 3, bq = tid & 7;
  int wv = vl >> 1, qq = vl & 1;
  int vo = (bx << 3) + vl;
  float cb1 = 0.f, cb2 = 0.f, cbt = 0.f;
  if (tid < 64) { cb1 = bf1[vo]; cb2 = bf2[vo]; cbt = bta[vo] + btb[vo]; }

  // init h state (sc-stores so later sc-loads observe it)
  if (tid < 64) ast(&hbuf[(bx << 6) + tid], hx[(bx << 6) + tid]);

  float prv[8];
  if (lane == 0) {
    #pragma unroll
    for (int b = 0; b < 8; ++b) prv[b] = pre[((long)b * NS) * NBB + j1];
  }
  gbar3(bar, bx, ++tick);

  for (int t = 0; t < NS; ++t) {
    // ---- stage h into LDS (batched 8B sc-loads: one latency exposure) ----
    {
      float2 rv[16];
      #pragma unroll
      for (int i = 0; i < 16; ++i) rv[i] = ald2(&hbuf[(((i << 8) + tid) << 1)]);
      #pragma unroll
      for (int i = 0; i < 16; ++i) ls2[(i << 8) + tid] = rv[i];
    }
    __syncthreads();

    // ---- stage 1: bb = lecun_tanh(pre + h @ W_hh) ----
    float a1[8];
    #pragma unroll
    for (int b = 0; b < 8; ++b) a1[b] = 0.f;
    #pragma unroll
    for (int c = 0; c < 4; ++c) {
      int idx = (c << 6) + lane;
      float4 w = wreg[c];
      #pragma unroll
      for (int b = 0; b < 8; ++b) {
        float4 hv = ls4[(b << 8) + idx];
        a1[b] += w.x * hv.x + w.y * hv.y + w.z * hv.z + w.w * hv.w;
      }
    }
    #pragma unroll
    for (int m = 1; m < 64; m <<= 1)
      #pragma unroll
      for (int b = 0; b < 8; ++b) a1[b] += __shfl_xor(a1[b], m);
    if (lane == 0) {
      #pragma unroll
      for (int b = 0; b < 8; ++b) {
        float s = a1[b] + prv[b];
        ast(&bbf[b * NBB + j1], 1.7159f * tanhf(0.666f * s));
      }
    }
    gbar3(bar, bx, ++tick);

    // ---- stage bb into LDS ----
    {
      float2 rv[8];
      #pragma unroll
      for (int i = 0; i < 8; ++i) rv[i] = ald2(&bbf[(((i << 8) + tid) << 1)]);
      #pragma unroll
      for (int i = 0; i < 8; ++i) ls2[(i << 8) + tid] = rv[i];
    }
    __syncthreads();

    // ---- stage 2: heads + h update ----
    // idx = c*8 + jsub: phase-group lanes (jsub 0..7) read consecutive 16B
    // -> conflict-free (was jsub*16+c: 256B stride -> 8-way bank conflict)
    float a2[8];
    #pragma unroll
    for (int b = 0; b < 8; ++b) a2[b] = 0.f;
    #pragma unroll
    for (int c = 0; c < 16; ++c) {
      int idx = (c << 3) + jsub;
      float4 w = W24[idx];
      #pragma unroll
      for (int b = 0; b < 8; ++b) {
        float4 bv = ls4[(b << 7) + idx];
        a2[b] += w.x * bv.x + w.y * bv.y + w.z * bv.z + w.w * bv.w;
      }
    }
    #pragma unroll
    for (int m = 1; m < 8; m <<= 1)
      #pragma unroll
      for (int b = 0; b < 8; ++b) a2[b] += __shfl_xor(a2[b], m);
    if (jsub == 0) {
      #pragma unroll
      for (int b = 0; b < 8; ++b) lpart[wave][head][v2][b] = a2[b];
    }
    __syncthreads();
    if (tid < 64) {
      float d1 = lpart[wv][0][qq][bq] + cb1;
      float d2 = lpart[wv][1][qq][bq] + cb2;
      float dt = lpart[wv][2][qq][bq] + lpart[wv][3][qq][bq] + cbt;
      float f1 = 1.7159f * tanhf(0.666f * d1);
      float f2 = 1.7159f * tanhf(0.666f * d2);
      float ti = 1.f / (1.f + expf(-dt));
      float hn = f1 * (1.f - ti) + ti * f2;
      ast(&hbuf[bq * NU + vo], hn);
      if (vo < NE) cfc[((long)bq * NS + t) * NE + vo] = hn;   // normal store (read post-kernel)
    }
    // prefetch next step's pre while waiting is cheap (normal cached load)
    if (lane == 0 && t + 1 < NS) {
      #pragma unroll
      for (int b = 0; b < 8; ++b) prv[b] = pre[((long)b * NS + t + 1) * NBB + j1];
    }
    gbar3(bar, bx, ++tick);
  }
}

// ---------------- LIF gate + residual (writes x1 into d_out), copy hx ----------------
__global__ __launch_bounds__(256) void lif_kernel(
    const float* __restrict__ x, const float* __restrict__ cfc,
    const float* __restrict__ thr, const float* __restrict__ leak,
    const float* __restrict__ steep, const float* __restrict__ hbuf,
    float* __restrict__ x1, float* __restrict__ outTail)
{
  long i4 = (long)blockIdx.x * blockDim.x + threadIdx.x;  // float4 index
  float4 xv = ((const float4*)x)[i4];
  float4 cv = ((const float4*)cfc)[i4];
  int col = (int)((i4 << 2) % NE);
  float4 tv = *(const float4*)(thr + col);
  float4 lv = *(const float4*)(leak + col);
  float4 sv = *(const float4*)(steep + col);
  float4 r;
#define LIF1(comp) { \
    float th = fabsf(tv.comp) * 0.1f; \
    float ls = 1.f / (1.f + expf(-lv.comp)); \
    float sp = (sv.comp > 20.f) ? sv.comp : log1pf(expf(sv.comp)); \
    float fire = 1.f / (1.f + expf(-sp * (fabsf(cv.comp) - th))); \
    float gate = fire + ls * (1.f - fire); \
    r.comp = xv.comp + cv.comp * gate; }
  LIF1(x) LIF1(y) LIF1(z) LIF1(w)
#undef LIF1
  ((float4*)x1)[i4] = r;
  if (i4 < (NB * NU / 4)) {
    // hbuf was written with sc stores; read it back with sc loads
    const float* hp = hbuf + (i4 << 2);
    float4 hv; hv.x = ald(hp); hv.y = ald(hp + 1); hv.z = ald(hp + 2); hv.w = ald(hp + 3);
    ((float4*)outTail)[i4] = hv;
  }
}

// ---------------- launch ----------------
extern "C" void kernel_launch(void* const* d_in, const int* in_sizes, int n_in,
                              void* d_out, int out_size, void* d_ws, size_t ws_size,
                              hipStream_t stream) {
  (void)in_sizes; (void)n_in; (void)out_size; (void)ws_size;
  const float* x     = (const float*)d_in[0];
  const float* hx    = (const float*)d_in[1];
  const float* ln1g  = (const float*)d_in[2];
  const float* ln1b  = (const float*)d_in[3];
  const float* ln2g  = (const float*)d_in[4];
  const float* ln2b  = (const float*)d_in[5];
  const float* Wbb   = (const float*)d_in[6];
  const float* bbb   = (const float*)d_in[7];
  const float* Wff1  = (const float*)d_in[8];
  const float* bff1  = (const float*)d_in[9];
  const float* Wff2  = (const float*)d_in[10];
  const float* bff2  = (const float*)d_in[11];
  const float* Wta   = (const float*)d_in[12];
  const float* btaP  = (const float*)d_in[13];
  const float* Wtb   = (const float*)d_in[14];
  const float* btbP  = (const float*)d_in[15];
  const float* lthr  = (const float*)d_in[16];
  const float* lleak = (const float*)d_in[17];
  const float* lstp  = (const float*)d_in[18];
  const float* W1    = (const float*)d_in[19];
  const float* b1    = (const float*)d_in[20];
  const float* W2    = (const float*)d_in[21];
  const float* b2    = (const float*)d_in[22];

  char* base = (char*)d_ws;
  unsigned short* normedH = (unsigned short*)base;                   // [0, 25165824)
  float* pre   = (float*)(base + 25165824);                          // [25165824, 58720256)
  float* cfc   = (float*)(base + 58720256);                          // [58720256, 109051904)
  unsigned short* gelu = (unsigned short*)base;                      // [0, 100663296) after cfc consumed
  unsigned short* normedL = (unsigned short*)(base + 109051904);     // [109051904, 134217728)
  unsigned short* h2      = (unsigned short*)(base + 109051904);     // same slot, later phase
  unsigned short* wtbbH = (unsigned short*)(base + 134217728);       // 786432
  float* whhT  = (float*)(base + 135004160);                         // 2097152
  float* whT   = (float*)(base + 137101312);                         // 8388608
  unsigned short* w1t = (unsigned short*)(base + 145489920);         // 4718592
  unsigned short* w2t = (unsigned short*)(base + 150208512);         // 4718592
  float* hbuf  = (float*)(base + 154927104);                         // 32768
  float* bbf   = (float*)(base + 154959872);                         // 16384
  unsigned* bar = (unsigned*)(base + 154976256);                     // 4096 (barrier region)
  unsigned short* wtbbL = (unsigned short*)(base + 154980352);       // 786432 -> end 155766784
  float* xout  = (float*)d_out;
  float* outTail = xout + (size_t)NBS * NE;
  unsigned short* lnlo_dummy = (unsigned short*)base;                // scratch, overwritten by gelu

  dim3 b328(32, 8);
  // weight prep (transposed, K-contiguous layouts)
  tr_f32_bf16split<<<dim3(512/32, 768/32), b328, 0, stream>>>(Wbb, wtbbH, wtbbL, 768, 512);
  tr_f32<<<dim3(512/32, 1024/32), b328, 0, stream>>>(Wbb + 768*512, whhT, 1024, 512);
  tr_f32<<<dim3(1024/32, 512/32), b328, 0, stream>>>(Wff1, whT + 0*(size_t)NU*NBB, 512, 1024);
  tr_f32<<<dim3(1024/32, 512/32), b328, 0, stream>>>(Wff2, whT + 1*(size_t)NU*NBB, 512, 1024);
  tr_f32<<<dim3(1024/32, 512/32), b328, 0, stream>>>(Wta,  whT + 2*(size_t)NU*NBB, 512, 1024);
  tr_f32<<<dim3(1024/32, 512/32), b328, 0, stream>>>(Wtb,  whT + 3*(size_t)NU*NBB, 512, 1024);
  tr_f32_bf16<<<dim3(3072/32, 768/32), b328, 0, stream>>>(W1, w1t, 768, 3072);
  tr_f32_bf16<<<dim3(768/32, 3072/32), b328, 0, stream>>>(W2, w2t, 3072, 768);

  // LN1 (hi/lo split) + input-projection precompute in ~fp32 precision:
  // pre = nH@wH + nH@wL + nL@wH + b_bb
  ln_kernel<<<NBS/4, 256, 0, stream>>>(x, ln1g, ln1b, normedH, normedL);
  gemm_bf16<0><<<(NBS/128)*(NBB/128), 256, 0, stream>>>(normedH, wtbbH, bbb, nullptr,
                                                        pre, nullptr, NBS, NBB, NE);
  gemm_bf16<3><<<(NBS/128)*(NBB/128), 256, 0, stream>>>(normedH, wtbbL, bbb, nullptr,
                                                        pre, nullptr, NBS, NBB, NE);
  gemm_bf16<3><<<(NBS/128)*(NBB/128), 256, 0, stream>>>(normedL, wtbbH, bbb, nullptr,
                                                        pre, nullptr, NBS, NBB, NE);

  hipMemsetAsync(bar, 0, 4096, stream);

  scan_kernel<<<NWG, 256, 0, stream>>>(pre, whhT, whT, bff1, bff2, btaP, btbP, hx,
                                       hbuf, bbf, cfc, bar);

  // LIF gate + residual -> x1 (stored in d_out), plus new_hx copy to output tail
  lif_kernel<<<(NBS*NE/4)/256, 256, 0, stream>>>(x, cfc, lthr, lleak, lstp, hbuf, xout, outTail);
  // LN2 + MLP with fused GELU and residual
  ln_kernel<<<NBS/4, 256, 0, stream>>>(xout, ln2g, ln2b, h2, lnlo_dummy);
  gemm_bf16<1><<<(NBS/128)*(NH/128), 256, 0, stream>>>(h2, w1t, b1, nullptr,
                                                       nullptr, gelu, NBS, NH, NE);
  gemm_bf16<2><<<(NBS/128)*(NE/128), 256, 0, stream>>>(gelu, w2t, b2, xout,
                                                       xout, nullptr, NBS, NE, NH);
}

// Round 5
// 21564.215 us; speedup vs baseline: 4.1736x; 1.1038x over previous
//
#include <hip/hip_runtime.h>
#include <math.h>

#define NB 8
#define NS 2048
#define NE 768
#define NU 1024
#define NBB 512
#define NH 3072
#define NBS (NB*NS)   // 16384
#define NWG 128

typedef float f32x4v __attribute__((ext_vector_type(4)));
typedef __bf16 bf16x8v __attribute__((ext_vector_type(8)));
typedef unsigned short u16x8v __attribute__((ext_vector_type(8)));
typedef unsigned short u16x4v __attribute__((ext_vector_type(4)));

__device__ __forceinline__ unsigned short f2bf(float f) {
  unsigned int u = __builtin_bit_cast(unsigned int, f);
  u = (u + 0x7fffu + ((u >> 16) & 1u)) >> 16;
  return (unsigned short)u;
}
__device__ __forceinline__ float bf2f(unsigned short h) {
  unsigned int u = ((unsigned int)h) << 16;
  return __builtin_bit_cast(float, u);
}

// agent-scope (device) relaxed ops: compile to sc0 sc1 loads/stores (coherent
// at LLC, no L2 writeback/invalidate instructions).
__device__ __forceinline__ float ald(const float* p) {
  return __hip_atomic_load((const float*)p, __ATOMIC_RELAXED, __HIP_MEMORY_SCOPE_AGENT);
}
__device__ __forceinline__ void ast(float* p, float v) {
  __hip_atomic_store(p, v, __ATOMIC_RELAXED, __HIP_MEMORY_SCOPE_AGENT);
}
__device__ __forceinline__ float2 ald2(const float* p) {
  unsigned long long v = __hip_atomic_load((const unsigned long long*)p,
                             __ATOMIC_RELAXED, __HIP_MEMORY_SCOPE_AGENT);
  return __builtin_bit_cast(float2, v);
}
__device__ __forceinline__ unsigned aldu(const unsigned* p) {
  return __hip_atomic_load(p, __ATOMIC_RELAXED, __HIP_MEMORY_SCOPE_AGENT);
}
__device__ __forceinline__ void astu(unsigned* p, unsigned v) {
  __hip_atomic_store(p, v, __ATOMIC_RELAXED, __HIP_MEMORY_SCOPE_AGENT);
}

// ---------------- leader/flag grid barrier ----------------
// Arrival: one relaxed agent store to slot[bx] (prior sc-stores drained by
// __syncthreads' vmcnt(0)). Detection: ONLY block 0's wave-0 gathers the 128
// slots (2 loads/lane + shfl-min). Release: block 0 stores epoch flag; other
// blocks poll the single flag line with ONE thread. No RMW, no poll storm.
__device__ __forceinline__ void gbar4(unsigned* bar, int bx, unsigned tick) {
  __syncthreads();
  int tid = threadIdx.x;
  unsigned* flag = &bar[768];                 // own cacheline, far from slots
  if (bx == 0) {
    if (tid < 64) {
      if (tid == 0) astu(&bar[0], tick);      // leader's own arrival
      unsigned m;
      do {
        unsigned a = aldu(&bar[tid * 4]);
        unsigned b = aldu(&bar[(tid + 64) * 4]);
        m = a < b ? a : b;
        #pragma unroll
        for (int s = 1; s < 64; s <<= 1) {
          unsigned o = __shfl_xor(m, s);
          m = m < o ? m : o;
        }
        if (m < tick) __builtin_amdgcn_s_sleep(1);
      } while (m < tick);
      if (tid == 0) astu(flag, tick);         // release
    }
  } else {
    if (tid == 0) {
      astu(&bar[bx * 4], tick);               // arrival
      while (aldu(flag) < tick) __builtin_amdgcn_s_sleep(1);
    }
  }
  __syncthreads();
}

// ---------------- transpose kernels (weight prep) ----------------
__global__ __launch_bounds__(256) void tr_f32(const float* __restrict__ in,
                                              float* __restrict__ out, int R, int C) {
  __shared__ float tile[32][33];
  int c0 = blockIdx.x * 32, r0 = blockIdx.y * 32;
  int tx = threadIdx.x, ty = threadIdx.y;  // block (32,8)
  #pragma unroll
  for (int i = 0; i < 32; i += 8)
    tile[ty + i][tx] = in[(long)(r0 + ty + i) * C + c0 + tx];
  __syncthreads();
  #pragma unroll
  for (int i = 0; i < 32; i += 8)
    out[(long)(c0 + ty + i) * R + r0 + tx] = tile[tx][ty + i];
}

__global__ __launch_bounds__(256) void tr_f32_bf16(const float* __restrict__ in,
                                                   unsigned short* __restrict__ out, int R, int C) {
  __shared__ float tile[32][33];
  int c0 = blockIdx.x * 32, r0 = blockIdx.y * 32;
  int tx = threadIdx.x, ty = threadIdx.y;
  #pragma unroll
  for (int i = 0; i < 32; i += 8)
    tile[ty + i][tx] = in[(long)(r0 + ty + i) * C + c0 + tx];
  __syncthreads();
  #pragma unroll
  for (int i = 0; i < 32; i += 8)
    out[(long)(c0 + ty + i) * R + r0 + tx] = f2bf(tile[tx][ty + i]);
}

// transpose + split into bf16 hi/lo pair (for ~fp32-precision GEMM)
__global__ __launch_bounds__(256) void tr_f32_bf16split(const float* __restrict__ in,
    unsigned short* __restrict__ oh, unsigned short* __restrict__ ol, int R, int C) {
  __shared__ float tile[32][33];
  int c0 = blockIdx.x * 32, r0 = blockIdx.y * 32;
  int tx = threadIdx.x, ty = threadIdx.y;
  #pragma unroll
  for (int i = 0; i < 32; i += 8)
    tile[ty + i][tx] = in[(long)(r0 + ty + i) * C + c0 + tx];
  __syncthreads();
  #pragma unroll
  for (int i = 0; i < 32; i += 8) {
    float v = tile[tx][ty + i];
    unsigned short h = f2bf(v);
    long idx = (long)(c0 + ty + i) * R + r0 + tx;
    oh[idx] = h;
    ol[idx] = f2bf(v - bf2f(h));
  }
}

// ---------------- LayerNorm (one wave per row of 768) -> bf16 hi/lo out ----------------
__global__ __launch_bounds__(256) void ln_kernel(const float* __restrict__ in,
    const float* __restrict__ gw, const float* __restrict__ bw,
    unsigned short* __restrict__ outh, unsigned short* __restrict__ outl) {
  int lane = threadIdx.x & 63;
  long row = (long)blockIdx.x * 4 + (threadIdx.x >> 6);
  const float4* rp = (const float4*)(in + row * NE);
  float4 v[3];
  float s = 0.f, sq = 0.f;
  #pragma unroll
  for (int j = 0; j < 3; ++j) {
    v[j] = rp[lane + j * 64];
    s += v[j].x + v[j].y + v[j].z + v[j].w;
    sq += v[j].x*v[j].x + v[j].y*v[j].y + v[j].z*v[j].z + v[j].w*v[j].w;
  }
  #pragma unroll
  for (int m = 1; m < 64; m <<= 1) { s += __shfl_xor(s, m); sq += __shfl_xor(sq, m); }
  float mu = s * (1.f / NE);
  float rs = rsqrtf(sq * (1.f / NE) - mu * mu + 1e-5f);
  #pragma unroll
  for (int j = 0; j < 3; ++j) {
    int c4 = lane + j * 64;
    float4 g4 = ((const float4*)gw)[c4];
    float4 b4 = ((const float4*)bw)[c4];
    float f0 = (v[j].x - mu) * rs * g4.x + b4.x;
    float f1 = (v[j].y - mu) * rs * g4.y + b4.y;
    float f2 = (v[j].z - mu) * rs * g4.z + b4.z;
    float f3 = (v[j].w - mu) * rs * g4.w + b4.w;
    u16x4v oh, ol;
    oh[0] = f2bf(f0); ol[0] = f2bf(f0 - bf2f(oh[0]));
    oh[1] = f2bf(f1); ol[1] = f2bf(f1 - bf2f(oh[1]));
    oh[2] = f2bf(f2); ol[2] = f2bf(f2 - bf2f(oh[2]));
    oh[3] = f2bf(f3); ol[3] = f2bf(f3 - bf2f(oh[3]));
    *(u16x4v*)(outh + row * NE + (long)c4 * 4) = oh;
    *(u16x4v*)(outl + row * NE + (long)c4 * 4) = ol;
  }
}

// ---------------- bf16 MFMA GEMM: C[M,N] = A[M,K] @ Bt[N,K]^T (+bias, epilogue) ---
// EPI 0: Cf = acc + bias            (fp32 out)
// EPI 1: Cb = bf16(gelu(acc+bias))  (bf16 out)
// EPI 2: Cf = acc + bias + res      (fp32 out, residual add; res may alias Cf)
// EPI 3: Cf += acc                  (fp32 accumulate, no bias)
template<int EPI>
__global__ __launch_bounds__(256) void gemm_bf16(
    const unsigned short* __restrict__ A, const unsigned short* __restrict__ Bt,
    const float* __restrict__ bias, const float* res,
    float* Cf, unsigned short* Cb, int M, int N, int K)
{
  __shared__ unsigned short lA[128][72];
  __shared__ unsigned short lB[128][72];
  int tid = threadIdx.x;
  int lane = tid & 63, wave = tid >> 6;
  int wr = wave >> 1, wc = wave & 1;
  int r15 = lane & 15, hi = lane >> 4;
  int ntn = N >> 7;
  long m0 = (long)(blockIdx.x / ntn) << 7;
  long n0 = (long)(blockIdx.x % ntn) << 7;
  f32x4v acc[4][4];
  #pragma unroll
  for (int m = 0; m < 4; ++m)
    #pragma unroll
    for (int n = 0; n < 4; ++n) acc[m][n] = (f32x4v){0.f, 0.f, 0.f, 0.f};

  for (int kt = 0; kt < K; kt += 64) {
    u16x8v ra[4], rb[4];
    #pragma unroll
    for (int i = 0; i < 4; ++i) {
      int c = tid + (i << 8);
      int rw = c >> 3, ko = (c & 7) << 3;
      ra[i] = *(const u16x8v*)(A + (m0 + rw) * K + kt + ko);
      rb[i] = *(const u16x8v*)(Bt + (n0 + rw) * K + kt + ko);
    }
    __syncthreads();
    #pragma unroll
    for (int i = 0; i < 4; ++i) {
      int c = tid + (i << 8);
      int rw = c >> 3, ko = (c & 7) << 3;
      *(u16x8v*)(&lA[rw][ko]) = ra[i];
      *(u16x8v*)(&lB[rw][ko]) = rb[i];
    }
    __syncthreads();
    #pragma unroll
    for (int ks = 0; ks < 64; ks += 32) {
      bf16x8v af[4], bfr[4];
      #pragma unroll
      for (int m = 0; m < 4; ++m)
        af[m] = *(const bf16x8v*)(&lA[wr * 64 + m * 16 + r15][ks + hi * 8]);
      #pragma unroll
      for (int n = 0; n < 4; ++n)
        bfr[n] = *(const bf16x8v*)(&lB[wc * 64 + n * 16 + r15][ks + hi * 8]);
      #pragma unroll
      for (int m = 0; m < 4; ++m)
        #pragma unroll
        for (int n = 0; n < 4; ++n)
          acc[m][n] = __builtin_amdgcn_mfma_f32_16x16x32_bf16(af[m], bfr[n], acc[m][n], 0, 0, 0);
    }
  }
  #pragma unroll
  for (int m = 0; m < 4; ++m) {
    long rbase = m0 + wr * 64 + m * 16 + hi * 4;
    #pragma unroll
    for (int n = 0; n < 4; ++n) {
      long cg = n0 + wc * 64 + n * 16 + r15;
      float bs = (EPI == 3) ? 0.f : bias[cg];
      #pragma unroll
      for (int e = 0; e < 4; ++e) {
        long row = rbase + e;
        float vv = acc[m][n][e] + bs;
        if (EPI == 0) {
          Cf[row * N + cg] = vv;
        } else if (EPI == 1) {
          float gl = 0.5f * vv * (1.f + erff(vv * 0.70710678118f));
          Cb[row * N + cg] = f2bf(gl);
        } else if (EPI == 2) {
          Cf[row * N + cg] = vv + res[row * N + cg];
        } else {
          Cf[row * N + cg] += vv;
        }
      }
    }
  }
}

// ---------------- persistent scan kernel ----------------
// 128 WGs x 256 thr; 2 leader/flag barriers per timestep.
// Exchange data (hbuf/bbf) via agent-scope sc ops, staged into LDS per stage.
// ALL weights register-hoisted (stage1 wreg[4], stage2 w2reg[16]); no fences.
__global__ __launch_bounds__(256) void scan_kernel(
    const float* __restrict__ pre, const float* __restrict__ WhhT,
    const float* __restrict__ WhT,
    const float* __restrict__ bf1, const float* __restrict__ bf2,
    const float* __restrict__ bta, const float* __restrict__ btb,
    const float* __restrict__ hx,
    float* hbuf, float* bbf, float* __restrict__ cfc, unsigned* bar)
{
  __shared__ float lsd[NB * NU];            // h staging (32KB); bb reuses first 16KB
  __shared__ float lpart[4][4][2][8];
  int tid = threadIdx.x;
  int lane = tid & 63, wave = tid >> 6;
  int bx = blockIdx.x;
  int j1 = (bx << 2) + wave;
  int head = lane >> 4, v2 = (lane >> 3) & 1, jsub = lane & 7;
  int vg = (bx << 3) + (wave << 1) + v2;
  const float4* W14 = (const float4*)(WhhT + (long)j1 * NU);
  const float4* W24 = (const float4*)(WhT + ((long)head * NU + vg) * NBB);
  const float4* ls4 = (const float4*)lsd;
  float2* ls2 = (float2*)lsd;
  unsigned tick = 0;

  // hoist this wave's Whh row (4KB across 64 lanes -> 4 float4/lane)
  float4 wreg[4];
  #pragma unroll
  for (int c = 0; c < 4; ++c) wreg[c] = W14[(c << 6) + lane];
  // hoist stage-2 weight rows (16 float4/lane = 64 VGPR)
  float4 w2reg[16];
  #pragma unroll
  for (int c = 0; c < 16; ++c) w2reg[c] = W24[(c << 3) + jsub];

  // tail-update constants
  int vl = tid >> 3, bq = tid & 7;
  int wv = vl >> 1, qq = vl & 1;
  int vo = (bx << 3) + vl;
  float cb1 = 0.f, cb2 = 0.f, cbt = 0.f;
  if (tid < 64) { cb1 = bf1[vo]; cb2 = bf2[vo]; cbt = bta[vo] + btb[vo]; }

  // init h state (sc-stores so later sc-loads observe it)
  if (tid < 64) ast(&hbuf[(bx << 6) + tid], hx[(bx << 6) + tid]);

  float prv[8];
  if (lane == 0) {
    #pragma unroll
    for (int b = 0; b < 8; ++b) prv[b] = pre[((long)b * NS) * NBB + j1];
  }
  gbar4(bar, bx, ++tick);

  for (int t = 0; t < NS; ++t) {
    // ---- stage h into LDS (batched 8B sc-loads: one latency exposure) ----
    {
      float2 rv[16];
      #pragma unroll
      for (int i = 0; i < 16; ++i) rv[i] = ald2(&hbuf[(((i << 8) + tid) << 1)]);
      #pragma unroll
      for (int i = 0; i < 16; ++i) ls2[(i << 8) + tid] = rv[i];
    }
    __syncthreads();

    // ---- stage 1: bb = lecun_tanh(pre + h @ W_hh) ----
    float a1[8];
    #pragma unroll
    for (int b = 0; b < 8; ++b) a1[b] = 0.f;
    #pragma unroll
    for (int c = 0; c < 4; ++c) {
      int idx = (c << 6) + lane;
      float4 w = wreg[c];
      #pragma unroll
      for (int b = 0; b < 8; ++b) {
        float4 hv = ls4[(b << 8) + idx];
        a1[b] += w.x * hv.x + w.y * hv.y + w.z * hv.z + w.w * hv.w;
      }
    }
    #pragma unroll
    for (int m = 1; m < 64; m <<= 1)
      #pragma unroll
      for (int b = 0; b < 8; ++b) a1[b] += __shfl_xor(a1[b], m);
    if (lane == 0) {
      #pragma unroll
      for (int b = 0; b < 8; ++b) {
        float s = a1[b] + prv[b];
        ast(&bbf[b * NBB + j1], 1.7159f * tanhf(0.666f * s));
      }
    }
    gbar4(bar, bx, ++tick);

    // ---- stage bb into LDS ----
    {
      float2 rv[8];
      #pragma unroll
      for (int i = 0; i < 8; ++i) rv[i] = ald2(&bbf[(((i << 8) + tid) << 1)]);
      #pragma unroll
      for (int i = 0; i < 8; ++i) ls2[(i << 8) + tid] = rv[i];
    }
    __syncthreads();

    // ---- stage 2: heads + h update ----
    // idx = c*8 + jsub: phase-group lanes (jsub 0..7) read consecutive 16B
    // -> conflict-free LDS; weights in registers (w2reg)
    float a2[8];
    #pragma unroll
    for (int b = 0; b < 8; ++b) a2[b] = 0.f;
    #pragma unroll
    for (int c = 0; c < 16; ++c) {
      int idx = (c << 3) + jsub;
      float4 w = w2reg[c];
      #pragma unroll
      for (int b = 0; b < 8; ++b) {
        float4 bv = ls4[(b << 7) + idx];
        a2[b] += w.x * bv.x + w.y * bv.y + w.z * bv.z + w.w * bv.w;
      }
    }
    #pragma unroll
    for (int m = 1; m < 8; m <<= 1)
      #pragma unroll
      for (int b = 0; b < 8; ++b) a2[b] += __shfl_xor(a2[b], m);
    if (jsub == 0) {
      #pragma unroll
      for (int b = 0; b < 8; ++b) lpart[wave][head][v2][b] = a2[b];
    }
    __syncthreads();
    if (tid < 64) {
      float d1 = lpart[wv][0][qq][bq] + cb1;
      float d2 = lpart[wv][1][qq][bq] + cb2;
      float dt = lpart[wv][2][qq][bq] + lpart[wv][3][qq][bq] + cbt;
      float f1 = 1.7159f * tanhf(0.666f * d1);
      float f2 = 1.7159f * tanhf(0.666f * d2);
      float ti = 1.f / (1.f + expf(-dt));
      float hn = f1 * (1.f - ti) + ti * f2;
      ast(&hbuf[bq * NU + vo], hn);
      if (vo < NE) cfc[((long)bq * NS + t) * NE + vo] = hn;   // normal store (read post-kernel)
    }
    // prefetch next step's pre while waiting is cheap (normal cached load)
    if (lane == 0 && t + 1 < NS) {
      #pragma unroll
      for (int b = 0; b < 8; ++b) prv[b] = pre[((long)b * NS + t + 1) * NBB + j1];
    }
    gbar4(bar, bx, ++tick);
  }
}

// ---------------- LIF gate + residual (writes x1 into d_out), copy hx ----------------
__global__ __launch_bounds__(256) void lif_kernel(
    const float* __restrict__ x, const float* __restrict__ cfc,
    const float* __restrict__ thr, const float* __restrict__ leak,
    const float* __restrict__ steep, const float* __restrict__ hbuf,
    float* __restrict__ x1, float* __restrict__ outTail)
{
  long i4 = (long)blockIdx.x * blockDim.x + threadIdx.x;  // float4 index
  float4 xv = ((const float4*)x)[i4];
  float4 cv = ((const float4*)cfc)[i4];
  int col = (int)((i4 << 2) % NE);
  float4 tv = *(const float4*)(thr + col);
  float4 lv = *(const float4*)(leak + col);
  float4 sv = *(const float4*)(steep + col);
  float4 r;
#define LIF1(comp) { \
    float th = fabsf(tv.comp) * 0.1f; \
    float ls = 1.f / (1.f + expf(-lv.comp)); \
    float sp = (sv.comp > 20.f) ? sv.comp : log1pf(expf(sv.comp)); \
    float fire = 1.f / (1.f + expf(-sp * (fabsf(cv.comp) - th))); \
    float gate = fire + ls * (1.f - fire); \
    r.comp = xv.comp + cv.comp * gate; }
  LIF1(x) LIF1(y) LIF1(z) LIF1(w)
#undef LIF1
  ((float4*)x1)[i4] = r;
  if (i4 < (NB * NU / 4)) {
    // hbuf was written with sc stores; read it back with sc loads
    const float* hp = hbuf + (i4 << 2);
    float4 hv; hv.x = ald(hp); hv.y = ald(hp + 1); hv.z = ald(hp + 2); hv.w = ald(hp + 3);
    ((float4*)outTail)[i4] = hv;
  }
}

// ---------------- launch ----------------
extern "C" void kernel_launch(void* const* d_in, const int* in_sizes, int n_in,
                              void* d_out, int out_size, void* d_ws, size_t ws_size,
                              hipStream_t stream) {
  (void)in_sizes; (void)n_in; (void)out_size; (void)ws_size;
  const float* x     = (const float*)d_in[0];
  const float* hx    = (const float*)d_in[1];
  const float* ln1g  = (const float*)d_in[2];
  const float* ln1b  = (const float*)d_in[3];
  const float* ln2g  = (const float*)d_in[4];
  const float* ln2b  = (const float*)d_in[5];
  const float* Wbb   = (const float*)d_in[6];
  const float* bbb   = (const float*)d_in[7];
  const float* Wff1  = (const float*)d_in[8];
  const float* bff1  = (const float*)d_in[9];
  const float* Wff2  = (const float*)d_in[10];
  const float* bff2  = (const float*)d_in[11];
  const float* Wta   = (const float*)d_in[12];
  const float* btaP  = (const float*)d_in[13];
  const float* Wtb   = (const float*)d_in[14];
  const float* btbP  = (const float*)d_in[15];
  const float* lthr  = (const float*)d_in[16];
  const float* lleak = (const float*)d_in[17];
  const float* lstp  = (const float*)d_in[18];
  const float* W1    = (const float*)d_in[19];
  const float* b1    = (const float*)d_in[20];
  const float* W2    = (const float*)d_in[21];
  const float* b2    = (const float*)d_in[22];

  char* base = (char*)d_ws;
  unsigned short* normedH = (unsigned short*)base;                   // [0, 25165824)
  float* pre   = (float*)(base + 25165824);                          // [25165824, 58720256)
  float* cfc   = (float*)(base + 58720256);                          // [58720256, 109051904)
  unsigned short* gelu = (unsigned short*)base;                      // [0, 100663296) after cfc consumed
  unsigned short* normedL = (unsigned short*)(base + 109051904);     // [109051904, 134217728)
  unsigned short* h2      = (unsigned short*)(base + 109051904);     // same slot, later phase
  unsigned short* wtbbH = (unsigned short*)(base + 134217728);       // 786432
  float* whhT  = (float*)(base + 135004160);                         // 2097152
  float* whT   = (float*)(base + 137101312);                         // 8388608
  unsigned short* w1t = (unsigned short*)(base + 145489920);         // 4718592
  unsigned short* w2t = (unsigned short*)(base + 150208512);         // 4718592
  float* hbuf  = (float*)(base + 154927104);                         // 32768
  float* bbf   = (float*)(base + 154959872);                         // 16384
  unsigned* bar = (unsigned*)(base + 154976256);                     // 4096 (slots + flag)
  unsigned short* wtbbL = (unsigned short*)(base + 154980352);       // 786432 -> end 155766784
  float* xout  = (float*)d_out;
  float* outTail = xout + (size_t)NBS * NE;
  unsigned short* lnlo_dummy = (unsigned short*)base;                // scratch, overwritten by gelu

  dim3 b328(32, 8);
  // weight prep (transposed, K-contiguous layouts)
  tr_f32_bf16split<<<dim3(512/32, 768/32), b328, 0, stream>>>(Wbb, wtbbH, wtbbL, 768, 512);
  tr_f32<<<dim3(512/32, 1024/32), b328, 0, stream>>>(Wbb + 768*512, whhT, 1024, 512);
  tr_f32<<<dim3(1024/32, 512/32), b328, 0, stream>>>(Wff1, whT + 0*(size_t)NU*NBB, 512, 1024);
  tr_f32<<<dim3(1024/32, 512/32), b328, 0, stream>>>(Wff2, whT + 1*(size_t)NU*NBB, 512, 1024);
  tr_f32<<<dim3(1024/32, 512/32), b328, 0, stream>>>(Wta,  whT + 2*(size_t)NU*NBB, 512, 1024);
  tr_f32<<<dim3(1024/32, 512/32), b328, 0, stream>>>(Wtb,  whT + 3*(size_t)NU*NBB, 512, 1024);
  tr_f32_bf16<<<dim3(3072/32, 768/32), b328, 0, stream>>>(W1, w1t, 768, 3072);
  tr_f32_bf16<<<dim3(768/32, 3072/32), b328, 0, stream>>>(W2, w2t, 3072, 768);

  // LN1 (hi/lo split) + input-projection precompute in ~fp32 precision:
  // pre = nH@wH + nH@wL + nL@wH + b_bb
  ln_kernel<<<NBS/4, 256, 0, stream>>>(x, ln1g, ln1b, normedH, normedL);
  gemm_bf16<0><<<(NBS/128)*(NBB/128), 256, 0, stream>>>(normedH, wtbbH, bbb, nullptr,
                                                        pre, nullptr, NBS, NBB, NE);
  gemm_bf16<3><<<(NBS/128)*(NBB/128), 256, 0, stream>>>(normedH, wtbbL, bbb, nullptr,
                                                        pre, nullptr, NBS, NBB, NE);
  gemm_bf16<3><<<(NBS/128)*(NBB/128), 256, 0, stream>>>(normedL, wtbbH, bbb, nullptr,
                                                        pre, nullptr, NBS, NBB, NE);

  hipMemsetAsync(bar, 0, 4096, stream);

  scan_kernel<<<NWG, 256, 0, stream>>>(pre, whhT, whT, bff1, bff2, btaP, btbP, hx,
                                       hbuf, bbf, cfc, bar);

  // LIF gate + residual -> x1 (stored in d_out), plus new_hx copy to output tail
  lif_kernel<<<(NBS*NE/4)/256, 256, 0, stream>>>(x, cfc, lthr, lleak, lstp, hbuf, xout, outTail);
  // LN2 + MLP with fused GELU and residual
  ln_kernel<<<NBS/4, 256, 0, stream>>>(xout, ln2g, ln2b, h2, lnlo_dummy);
  gemm_bf16<1><<<(NBS/128)*(NH/128), 256, 0, stream>>>(h2, w1t, b1, nullptr,
                                                       nullptr, gelu, NBS, NH, NE);
  gemm_bf16<2><<<(NBS/128)*(NE/128), 256, 0, stream>>>(gelu, w2t, b2, xout,
                                                       xout, nullptr, NBS, NE, NH);
}